// Round 17
// baseline (249.410 us; speedup 1.0000x reference)
//
#include <hip/hip_runtime.h>
#include <math.h>

#define Q_N 5000
#define S_N 1000
#define U_N 2000
#define D   100
#define B   32
#define T   100
#define NBT (B*(T-1))
#define NEG_F (-1e30f)

// stage-A/B block partitions (16 rows per block)
#define NB_Z2Q ((Q_N+15)/16)   // 313
#define NB_Z2U ((U_N+15)/16)   // 125
#define NB_Y1Q ((S_N+15)/16)   // 63
#define NB_Y1U ((Q_N+15)/16)   // 313
// packed bf16 Whh: 13 m-slices x 400 cols x 8 bf16
#define WB16_U16 (13*400*8)
#define WB16_F   (WB16_U16/2)
// kSetup partitions
#define NB_MK ((NBT+255)/256)        // 13
#define NB_PK ((WB16_U16+255)/256)   // 163
// kFuse batching
#define NB_FU (NBT/16)               // 198 exactly (3168 = 198*16)

// workspace layout (floats)
#define GPROJ_SZ (NBT*4*D)   // 1,267,200
#define H_SZ     (B*T*D)     //   320,000
#define QAGG_SZ  (Q_N*D)
#define UAGG_SZ  (U_N*D)
#define Z2Q_SZ   (Q_N*D)
#define Z2U_SZ   (U_N*D)
#define Y1Q_SZ   (S_N*D)
#define Y1U_SZ   (Q_N*D)

__device__ __forceinline__ void fma4(float4& a, float s, const float4 w) {
    a.x = fmaf(s, w.x, a.x); a.y = fmaf(s, w.y, a.y);
    a.z = fmaf(s, w.z, a.z); a.w = fmaf(s, w.w, a.w);
}
__device__ __forceinline__ float4 relu4(float4 v) {
    v.x = v.x > 0.f ? v.x : 0.f; v.y = v.y > 0.f ? v.y : 0.f;
    v.z = v.z > 0.f ? v.z : 0.f; v.w = v.w > 0.f ? v.w : 0.f;
    return v;
}
__device__ __forceinline__ float4 add4(float4 a, float4 b) {
    a.x += b.x; a.y += b.y; a.z += b.z; a.w += b.w; return a;
}
__device__ __forceinline__ float b2f_lo(unsigned u) { return __uint_as_float(u << 16); }
__device__ __forceinline__ float b2f_hi(unsigned u) { return __uint_as_float(u & 0xffff0000u); }

// ---------------------------------------------------------------------------
// NP=1 matvec (256 thr): dst[c]=relu(src@W+b). K split 8 ways. In-place safe.
// W may point to LDS (kRoot's cached layer-0) or global.
// ---------------------------------------------------------------------------
template<int K>
__device__ __forceinline__ void mv100_b256(const float* __restrict__ W,
                                           const float* __restrict__ bias,
                                           const float* __restrict__ src,
                                           float* __restrict__ dst,
                                           float* __restrict__ part)
{
    const int tid = threadIdx.x;
    const int c4  = tid & 31;
    const int ks  = tid >> 5;
    const int col0 = (4*c4 < 96) ? 4*c4 : 96;
    float4 acc = {0.f,0.f,0.f,0.f};
#pragma unroll 2
    for (int d = ks*4; d < K; d += 32) {
        const float4 sv = *(const float4*)&src[d];
        const float4 w0 = *(const float4*)&W[(d+0)*D + col0];
        const float4 w1 = *(const float4*)&W[(d+1)*D + col0];
        const float4 w2 = *(const float4*)&W[(d+2)*D + col0];
        const float4 w3 = *(const float4*)&W[(d+3)*D + col0];
        fma4(acc, sv.x, w0); fma4(acc, sv.y, w1);
        fma4(acc, sv.z, w2); fma4(acc, sv.w, w3);
    }
    *(float4*)&part[ks*D + col0] = acc;
    __syncthreads();
    if (tid < D) {
        float v = bias[tid];
#pragma unroll
        for (int k = 0; k < 8; ++k) v += part[k*D + tid];
        dst[tid] = v > 0.f ? v : 0.f;
    }
    __syncthreads();
}

// ---------------------------------------------------------------------------
// stage16: 16 rows of  out[v] = relu( (self[v] + sum_k f(v,k)*nbEmb[nb_k]) @ W + b )
// ---------------------------------------------------------------------------
struct __align__(16) Stage16 {
    float x[16*D];    // 6.4 KB
    int   nb[128];
    float fw[128];
};

template<int UQ_MODE>
__device__ __forceinline__ void stage16(Stage16& sh, int row0, int N,
        const float* __restrict__ selfEmb, const float* __restrict__ nbEmb,
        const int* __restrict__ tab,
        const float* __restrict__ uq, float wc, float wp, float wn,
        const float* __restrict__ W, const float* __restrict__ bias,
        float* __restrict__ out)
{
    const int tid = threadIdx.x;
    if (tid < 128) {
        const int i = tid >> 3, k = tid & 7;
        int v = row0 + i; if (v >= N) v = N - 1;
        const int nbv = tab[v*8 + k];
        sh.nb[tid] = nbv;
        float f = 0.125f;
        if (UQ_MODE == 1) {
            const float* w = &uq[(v*Q_N + nbv)*3];
            f = 0.125f*(wc*w[0] + wp*w[1] + wn*w[2]);
        } else if (UQ_MODE == 2) {
            const float* w = &uq[(nbv*Q_N + v)*3];
            f = 0.125f*(wc*w[0] + wp*w[1] + wn*w[2]);
        }
        sh.fw[tid] = f;
    }
    __syncthreads();
    const int c4   = tid & 31;
    const int rowg = tid >> 5;                     // 0..7
    const int col0 = (4*c4 < 96) ? 4*c4 : 96;
    // gather + mean + self  -> x
#pragma unroll
    for (int rr = 0; rr < 2; ++rr) {
        const int i = rowg + 8*rr;
        int v = row0 + i; if (v >= N) v = N - 1;
        float4 acc = *(const float4*)&selfEmb[v*D + col0];
#pragma unroll
        for (int k = 0; k < 8; ++k)
            fma4(acc, sh.fw[i*8 + k], *(const float4*)&nbEmb[sh.nb[i*8 + k]*D + col0]);
        *(float4*)&sh.x[i*D + col0] = acc;
    }
    __syncthreads();
    // 16 x D @ D x D  (2 rows, 4 cols per thread)
    float4 a0 = {0.f,0.f,0.f,0.f}, a1 = {0.f,0.f,0.f,0.f};
#pragma unroll 1
    for (int d = 0; d < D; d += 4) {
        const float4 w0 = *(const float4*)&W[(d+0)*D + col0];
        const float4 w1 = *(const float4*)&W[(d+1)*D + col0];
        const float4 w2 = *(const float4*)&W[(d+2)*D + col0];
        const float4 w3 = *(const float4*)&W[(d+3)*D + col0];
        const float4 s0 = *(const float4*)&sh.x[rowg*D + d];
        const float4 s1 = *(const float4*)&sh.x[(rowg+8)*D + d];
        fma4(a0, s0.x, w0); fma4(a0, s0.y, w1); fma4(a0, s0.z, w2); fma4(a0, s0.w, w3);
        fma4(a1, s1.x, w0); fma4(a1, s1.y, w1); fma4(a1, s1.z, w2); fma4(a1, s1.w, w3);
    }
    const float4 bb = *(const float4*)&bias[col0];
    {
        int v = row0 + rowg; if (v >= N) v = N - 1;
        *(float4*)&out[v*D + col0] = relu4(add4(a0, bb));
        v = row0 + rowg + 8; if (v >= N) v = N - 1;
        *(float4*)&out[v*D + col0] = relu4(add4(a1, bb));
    }
}

// ---------------------------------------------------------------------------
// kStageA: z2q | z2u | y1q_it0 | y1u_it0  (all independent)
// ---------------------------------------------------------------------------
__global__ __launch_bounds__(256, 6)
void kStageA(const int* __restrict__ qnb, const int* __restrict__ snb,
             const int* __restrict__ unb, const int* __restrict__ qnb2,
             const float* __restrict__ emb_q, const float* __restrict__ emb_q2,
             const float* __restrict__ emb_s, const float* __restrict__ emb_u,
             const float* __restrict__ uq,
             const float* __restrict__ wcp, const float* __restrict__ wpp,
             const float* __restrict__ wnp,
             const float* __restrict__ aggW, const float* __restrict__ aggB,
             float* __restrict__ z2q, float* __restrict__ z2u,
             float* __restrict__ y1q0, float* __restrict__ y1u0)
{
    __shared__ Stage16 sh;
    const float wc = wcp[0], wp = wpp[0], wn = wnp[0];
    int b = blockIdx.x;
    if (b < NB_Z2Q) {
        stage16<0>(sh, b*16, Q_N, emb_q, emb_s, qnb, uq, wc, wp, wn,
                   aggW + 2*D*D, aggB + 2*D, z2q);
        return;
    }
    b -= NB_Z2Q;
    if (b < NB_Z2U) {
        stage16<1>(sh, b*16, U_N, emb_u, emb_q2, unb, uq, wc, wp, wn,
                   aggW + 2*D*D, aggB + 2*D, z2u);
        return;
    }
    b -= NB_Z2U;
    if (b < NB_Y1Q) {
        stage16<0>(sh, b*16, S_N, emb_s, emb_q, snb, uq, wc, wp, wn,
                   aggW + 1*D*D, aggB + 1*D, y1q0);
        return;
    }
    b -= NB_Y1Q;
    stage16<2>(sh, b*16, Q_N, emb_q2, emb_u, qnb2, uq, wc, wp, wn,
               aggW + 1*D*D, aggB + 1*D, y1u0);
}

// ---------------------------------------------------------------------------
// kStageB: y1q_it1 | y1u_it1 (needs z2*, y1*_it0)
// ---------------------------------------------------------------------------
__global__ __launch_bounds__(256, 6)
void kStageB(const int* __restrict__ snb, const int* __restrict__ qnb2,
             const float* __restrict__ uq,
             const float* __restrict__ wcp, const float* __restrict__ wpp,
             const float* __restrict__ wnp,
             const float* __restrict__ aggW, const float* __restrict__ aggB,
             const float* __restrict__ z2q, const float* __restrict__ z2u,
             const float* __restrict__ y1q0, const float* __restrict__ y1u0,
             float* __restrict__ y1q1, float* __restrict__ y1u1)
{
    __shared__ Stage16 sh;
    const float wc = wcp[0], wp = wpp[0], wn = wnp[0];
    int b = blockIdx.x;
    if (b < NB_Y1Q) {
        stage16<0>(sh, b*16, S_N, y1q0, z2q, snb, uq, wc, wp, wn,
                   aggW + 1*D*D, aggB + 1*D, y1q1);
        return;
    }
    b -= NB_Y1Q;
    stage16<2>(sh, b*16, Q_N, y1u0, z2u, qnb2, uq, wc, wp, wn,
               aggW + 1*D*D, aggB + 1*D, y1u1);
}

// ---------------------------------------------------------------------------
// kMarkInit (separate: kSetup's mark phase depends on it)
// ---------------------------------------------------------------------------
__global__ void kMarkInit(int* __restrict__ marks)
{
    const int i = blockIdx.x*256 + threadIdx.x;
    if (i < Q_N + U_N) marks[i] = 0;
}

// ---------------------------------------------------------------------------
// kSetup: mark | pack-Whh-bf16 | fold  (independent phases, one launch)
// ---------------------------------------------------------------------------
__global__ __launch_bounds__(256)
void kSetup(const int* __restrict__ question, const int* __restrict__ user,
            int* __restrict__ qmark, int* __restrict__ umark,
            const float* __restrict__ Whh, ushort* __restrict__ wb,
            const float* __restrict__ keyW, const float* __restrict__ queryW,
            const float* __restrict__ attnW,
            float* __restrict__ vk, float* __restrict__ vq)
{
    int bkt = blockIdx.x;
    const int tid = threadIdx.x;
    if (bkt < NB_MK) {
        const int bt = bkt*256 + tid;
        if (bt < NBT) {
            const int b = bt / (T-1), t = bt % (T-1);
            qmark[question[b*T + t]] = 1;
            umark[user[b*T + t]] = 1;
        }
        return;
    }
    bkt -= NB_MK;
    if (bkt < NB_PK) {
        const int i = bkt*256 + tid;          // ((m*400)+col)*8 + j
        if (i < WB16_U16) {
            const int j  = i & 7;
            const int mc = i >> 3;
            const int m  = mc / 400;
            const int col = mc - m*400;
            const int d  = 8*m + j;
            ushort v = 0;
            if (d < D) {
                unsigned u = __float_as_uint(Whh[d*4*D + col]);
                const unsigned lsb = (u >> 16) & 1u;
                u += 0x7fffu + lsb;            // round-to-nearest-even
                v = (ushort)(u >> 16);
            }
            wb[i] = v;
        }
        return;
    }
    // fold
    if (tid < D) {
        float a = 0.f;
        for (int e = 0; e < D; ++e) a = fmaf(keyW[tid*D + e], attnW[e], a);
        vk[tid] = a;
    } else if (tid < 2*D) {
        const int d = tid - D;
        float a = 0.f;
        for (int e = 0; e < D; ++e) a = fmaf(queryW[d*D + e], attnW[D + e], a);
        vq[d] = a;
    }
}

// ---------------------------------------------------------------------------
// kRoot: per marked root, 3 root updates + final layer.
// aggW layer-0 (used 3x serially) is cached in LDS once per block:
// cuts ~2/3 of the per-block 200KB L2 weight streaming. 43.7KB LDS ->
// 3 blocks/CU.
// ---------------------------------------------------------------------------
struct __align__(16) RootSh {
    float w0[D*D];    // 40 KB cached aggW layer 0
    float e0[D];
    float part[8*D];
    int   nb[8];
    float fw[8];
};

template<bool WEIGHTED>
__device__ __forceinline__ void rootchain(RootSh& sh, int root,
        const int* __restrict__ tab,
        const float* __restrict__ selfEmb, const float* __restrict__ lvl1Emb,
        const float* __restrict__ y0, const float* __restrict__ y1,
        const float* __restrict__ W0, const float* __restrict__ b0,
        const float* __restrict__ WL, const float* __restrict__ bL,
        const float* __restrict__ uq, float wc, float wp, float wn,
        float* __restrict__ outrow)
{
    const int tid = threadIdx.x;
    // stage W0 -> LDS (coalesced float4), overlapped with nb/fw setup
    {
        const float4* src = (const float4*)W0;
        float4* dst = (float4*)sh.w0;
#pragma unroll 1
        for (int i = tid; i < D*D/4; i += 256) dst[i] = src[i];
    }
    if (tid < 8) {
        const int a = tab[root*8 + tid];
        sh.nb[tid] = a;
        float f = 0.125f;
        if (WEIGHTED) {
            const float* w = &uq[(root*Q_N + a)*3];
            f = 0.125f*(wc*w[0] + wp*w[1] + wn*w[2]);
        }
        sh.fw[tid] = f;
    }
    __syncthreads();
    const int c4 = tid & 31;
    const int col0 = (4*c4 < 96) ? 4*c4 : 96;
    // m0
    if (tid < 32) {
        float4 acc = *(const float4*)&selfEmb[root*D + col0];
#pragma unroll
        for (int k = 0; k < 8; ++k)
            fma4(acc, sh.fw[k], *(const float4*)&lvl1Emb[sh.nb[k]*D + col0]);
        *(float4*)&sh.e0[col0] = acc;
    }
    __syncthreads();
    mv100_b256<D>(sh.w0, b0, sh.e0, sh.e0, sh.part);
    // m1
    if (tid < 32) {
        float4 acc = *(const float4*)&sh.e0[col0];
#pragma unroll
        for (int k = 0; k < 8; ++k)
            fma4(acc, sh.fw[k], *(const float4*)&y0[sh.nb[k]*D + col0]);
        *(float4*)&sh.e0[col0] = acc;
    }
    __syncthreads();
    mv100_b256<D>(sh.w0, b0, sh.e0, sh.e0, sh.part);
    // m2
    if (tid < 32) {
        float4 acc = *(const float4*)&sh.e0[col0];
#pragma unroll
        for (int k = 0; k < 8; ++k)
            fma4(acc, sh.fw[k], *(const float4*)&y1[sh.nb[k]*D + col0]);
        *(float4*)&sh.e0[col0] = acc;
    }
    __syncthreads();
    mv100_b256<D>(sh.w0, b0, sh.e0, sh.e0, sh.part);
    // final layer (WL streamed from L2) -> global
    mv100_b256<D>(WL, bL, sh.e0, outrow, sh.part);
}

__global__ __launch_bounds__(256, 3)
void kRoot(const int* __restrict__ qmark, const int* __restrict__ umark,
           const int* __restrict__ qnb, const int* __restrict__ unb,
           const float* __restrict__ emb_q, const float* __restrict__ emb_u,
           const float* __restrict__ emb_s, const float* __restrict__ emb_q2,
           const float* __restrict__ y1q0, const float* __restrict__ y1q1,
           const float* __restrict__ y1u0, const float* __restrict__ y1u1,
           const float* __restrict__ uq,
           const float* __restrict__ wcp, const float* __restrict__ wpp,
           const float* __restrict__ wnp,
           const float* __restrict__ aggW, const float* __restrict__ aggB,
           const float* __restrict__ aggLW, const float* __restrict__ aggLb,
           float* __restrict__ qagg, float* __restrict__ uagg)
{
    __shared__ RootSh sh;
    const int b = blockIdx.x;
    if (b < Q_N) {
        if (!qmark[b]) return;
        rootchain<false>(sh, b, qnb, emb_q, emb_s, y1q0, y1q1,
                         aggW, aggB, aggLW, aggLb,
                         uq, 0.f, 0.f, 0.f, qagg + b*D);
    } else {
        const int u = b - Q_N;
        if (!umark[u]) return;
        rootchain<true>(sh, u, unb, emb_u, emb_q2, y1u0, y1u1,
                        aggW, aggB, aggLW, aggLb,
                        uq, wcp[0], wpp[0], wnp[0], uagg + u*D);
    }
}

// ---------------------------------------------------------------------------
// kFuse: 16 (b,t) rows per block (198 blocks). Stages xcat + evec^T in LDS
// so fusW/Wih are streamed ONCE per 16 rows (L2 traffic /16 vs per-row).
//  phase0: x[16][200] = [w1*qagg+w2*uagg | emb_r]
//  phase1: evecT[k][i] = relu(x @ fusW + fusb)^T
//  phase2: gproj[bt] = evec @ Wih + bih   (rows inner, Wih reused in regs)
// ---------------------------------------------------------------------------
__global__ __launch_bounds__(256)
void kFuse(const int* __restrict__ question, const int* __restrict__ user,
           const int* __restrict__ response,
           const float* __restrict__ qagg, const float* __restrict__ uagg,
           const float* __restrict__ emb_r,
           const float* __restrict__ w1p, const float* __restrict__ w2p,
           const float* __restrict__ fusW, const float* __restrict__ fusb,
           const float* __restrict__ Wih, const float* __restrict__ bih,
           float* __restrict__ gproj)
{
    __shared__ __align__(16) float x[16][2*D];      // 12.8 KB
    __shared__ __align__(16) float evecT[D][20];    // 8 KB (16 rows + 4 pad)
    const int row0 = blockIdx.x * 16;
    const int tid = threadIdx.x;
    const float w1 = w1p[0], w2 = w2p[0];
    // phase 0: gather 16 xcat rows (50 float4 per row)
#pragma unroll 1
    for (int idx = tid; idx < 16*50; idx += 256) {
        const int i = idx / 50, c4 = idx - i*50;
        const int bt = row0 + i;
        const int b = bt / (T-1), t = bt - b*(T-1);
        const int col0 = c4*4;
        float4 v;
        if (col0 < D) {
            const int q = question[b*T + t];
            const int u = user[b*T + t];
            const float4 qa = *(const float4*)&qagg[q*D + col0];
            const float4 ua = *(const float4*)&uagg[u*D + col0];
            v.x = w1*qa.x + w2*ua.x; v.y = w1*qa.y + w2*ua.y;
            v.z = w1*qa.z + w2*ua.z; v.w = w1*qa.w + w2*ua.w;
        } else {
            const int r = response[b*T + t];
            v = *(const float4*)&emb_r[r*D + (col0 - D)];
        }
        *(float4*)&x[i][col0] = v;
    }
    __syncthreads();
    // phase 1: 16 x 200 @ 200 x 100 -> evecT (transposed store)
    {
        const int c4 = tid & 31;
        const int rowg = tid >> 5;
        const int col0 = (4*c4 < 96) ? 4*c4 : 96;
        float4 a0 = {0.f,0.f,0.f,0.f}, a1 = {0.f,0.f,0.f,0.f};
#pragma unroll 2
        for (int d = 0; d < 2*D; d += 4) {
            const float4 w0v = *(const float4*)&fusW[(d+0)*D + col0];
            const float4 w1v = *(const float4*)&fusW[(d+1)*D + col0];
            const float4 w2v = *(const float4*)&fusW[(d+2)*D + col0];
            const float4 w3v = *(const float4*)&fusW[(d+3)*D + col0];
            const float4 s0 = *(const float4*)&x[rowg][d];
            const float4 s1 = *(const float4*)&x[rowg+8][d];
            fma4(a0, s0.x, w0v); fma4(a0, s0.y, w1v);
            fma4(a0, s0.z, w2v); fma4(a0, s0.w, w3v);
            fma4(a1, s1.x, w0v); fma4(a1, s1.y, w1v);
            fma4(a1, s1.z, w2v); fma4(a1, s1.w, w3v);
        }
        const float4 bb = *(const float4*)&fusb[col0];
        a0 = relu4(add4(a0, bb)); a1 = relu4(add4(a1, bb));
        evecT[col0+0][rowg] = a0.x; evecT[col0+1][rowg] = a0.y;
        evecT[col0+2][rowg] = a0.z; evecT[col0+3][rowg] = a0.w;
        evecT[col0+0][rowg+8] = a1.x; evecT[col0+1][rowg+8] = a1.y;
        evecT[col0+2][rowg+8] = a1.z; evecT[col0+3][rowg+8] = a1.w;
    }
    __syncthreads();
    // phase 2: gproj rows = evec @ Wih + bih. thread = (col-chunk, row-half);
    // Wih float4 loaded once per k feeds 8 rows (L2 traffic = Wih once/block).
    {
        const int c  = tid & 127;          // col chunk (0..99 active)
        const int rh = tid >> 7;           // 0,1 -> rows rh*8 .. rh*8+7
        if (c < D) {
            const int col0 = 4*c;
            float4 acc[8];
#pragma unroll
            for (int r = 0; r < 8; ++r) acc[r] = {0.f,0.f,0.f,0.f};
#pragma unroll 2
            for (int k = 0; k < D; ++k) {
                const float4 wv = *(const float4*)&Wih[k*4*D + col0];
                const float4 e0 = *(const float4*)&evecT[k][rh*8];
                const float4 e1 = *(const float4*)&evecT[k][rh*8 + 4];
                fma4(acc[0], e0.x, wv); fma4(acc[1], e0.y, wv);
                fma4(acc[2], e0.z, wv); fma4(acc[3], e0.w, wv);
                fma4(acc[4], e1.x, wv); fma4(acc[5], e1.y, wv);
                fma4(acc[6], e1.z, wv); fma4(acc[7], e1.w, wv);
            }
            const float4 bb = *(const float4*)&bih[col0];
#pragma unroll
            for (int r = 0; r < 8; ++r) {
                const int bt = row0 + rh*8 + r;
                *(float4*)&gproj[bt*4*D + col0] = add4(acc[r], bb);
            }
        }
    }
}

// ---------------------------------------------------------------------------
// kB: LSTM scan, one block per b, 512 threads (400 active).
// PROVEN BEST (r13/r16: 89.5-89.8us, VGPR=88). bf16 weights (13 named uint4
// = 52 VGPR) resident under waves_per_eu(2,2); h read as LDS float4
// broadcasts; nonlinearity fused into the matvec phase. Structural ceiling
// for the 1-block-per-b layout: LDS-broadcast pipe ~1900 cy/step.
// ---------------------------------------------------------------------------
#define KB_LDW(m) const uint4 W##m = wp[m*400 + col];
#define KB_FMA(m) { const float4 h0 = *(const float4*)&hbuf[8*m]; \
                    const float4 h1 = *(const float4*)&hbuf[8*m + 4]; \
    a0 = fmaf(h0.x, b2f_lo(W##m.x), a0); \
    a1 = fmaf(h0.y, b2f_hi(W##m.x), a1); \
    a2 = fmaf(h0.z, b2f_lo(W##m.y), a2); \
    a3 = fmaf(h0.w, b2f_hi(W##m.y), a3); \
    a0 = fmaf(h1.x, b2f_lo(W##m.z), a0); \
    a1 = fmaf(h1.y, b2f_hi(W##m.z), a1); \
    a2 = fmaf(h1.z, b2f_lo(W##m.w), a2); \
    a3 = fmaf(h1.w, b2f_hi(W##m.w), a3); }

__global__ __attribute__((amdgpu_flat_work_group_size(512, 512)))
           __attribute__((amdgpu_waves_per_eu(2, 2)))
void kB(const float* __restrict__ gproj, const ushort* __restrict__ wb,
        const float* __restrict__ bhh, float* __restrict__ H)
{
    __shared__ __align__(16) float hbuf[104];     // [100..103] stay 0 (pad)
    __shared__ float gates[4*D];                  // post-nonlinearity values
    const int b = blockIdx.x;
    const int tid = threadIdx.x;
    const bool on = tid < 4*D;
    const int col = on ? tid : (4*D - 1);
    const float bb = bhh[col];
    const bool isG = (col >= 2*D) && (col < 3*D); // gg column -> tanh
    const uint4* wp = (const uint4*)wb;
    // hoisted loop-invariant bf16 weights (13 x uint4 = 52 VGPR, resident)
    KB_LDW(0)  KB_LDW(1)  KB_LDW(2)  KB_LDW(3)  KB_LDW(4)  KB_LDW(5)
    KB_LDW(6)  KB_LDW(7)  KB_LDW(8)  KB_LDW(9)  KB_LDW(10) KB_LDW(11)
    KB_LDW(12)
    float creg = 0.f;
    if (tid < 104) hbuf[tid] = 0.f;
    float g = on ? gproj[(b*(T-1) + 0)*4*D + col] : 0.f;
    __syncthreads();
#pragma unroll 1
    for (int t = 0; t < T-1; ++t) {
        if (on) {
            float a0 = g + bb, a1 = 0.f, a2 = 0.f, a3 = 0.f;
            KB_FMA(0)  KB_FMA(1)  KB_FMA(2)  KB_FMA(3)  KB_FMA(4)  KB_FMA(5)
            KB_FMA(6)  KB_FMA(7)  KB_FMA(8)  KB_FMA(9)  KB_FMA(10) KB_FMA(11)
            KB_FMA(12)
            const float tot = (a0 + a1) + (a2 + a3);
            gates[col] = isG ? tanhf(tot) : 1.f/(1.f + expf(-tot));
        }
        __syncthreads();
        // prefetch next step's gproj under the combine phase
        if (t + 1 < T-1 && on) g = gproj[(b*(T-1) + t + 1)*4*D + col];
        if (tid < D) {
            const float ig = gates[tid];
            const float fg = gates[D   + tid];
            const float gg = gates[2*D + tid];
            const float og = gates[3*D + tid];
            const float cn = fg*creg + ig*gg;
            const float hn = og*tanhf(cn);
            creg = cn;
            hbuf[tid] = hn;
            H[(b*T + t)*D + tid] = hn;
        }
        __syncthreads();
    }
}

// ---------------------------------------------------------------------------
// kC: prediction head per (b,t): scores -> top-10 -> attention -> sigmoid
// ---------------------------------------------------------------------------
__global__ __launch_bounds__(128)
void kC(const int* __restrict__ question, const int* __restrict__ skill_tab,
        const float* __restrict__ emb_q, const float* __restrict__ emb_s,
        const float* __restrict__ H, const float* __restrict__ vk,
        const float* __restrict__ vq, float* __restrict__ out)
{
    __shared__ __align__(16) float qs[5*D];
    __shared__ __align__(16) float hist[11*D];
    __shared__ float scores[T];
    __shared__ float kdot[5], qdot[11];
    __shared__ int   topi[10];
    __shared__ float topv[10];
    const int blk = blockIdx.x;
    const int b = blk / (T-1);
    const int t = blk % (T-1);
    const int tid = threadIdx.x;
    const int qn = question[b*T + t + 1];

    for (int i = tid; i < 5*D; i += 128) {
        const int rr = i / D, d = i % D;
        if (rr == 0) qs[i] = emb_q[qn*D + d];
        else         qs[i] = emb_s[skill_tab[qn*4 + (rr-1)]*D + d];
    }
    __syncthreads();

    for (int tau = tid; tau < T; tau += 128) {
        float sc = NEG_F;
        if (tau < t) {
            const float4* rowp = (const float4*)&emb_q[question[b*T + tau]*D];
            float acc = 0.f;
#pragma unroll 1
            for (int d4 = 0; d4 < D/4; ++d4) {
                const float4 a  = rowp[d4];
                const float4 qv = *(const float4*)&qs[d4*4];
                acc += a.x*qv.x + a.y*qv.y + a.z*qv.z + a.w*qv.w;
            }
            sc = acc;
        }
        scores[tau] = sc;
    }
    __syncthreads();

    // top-10 (lowest-index wins ties; only the selected SET matters)
    for (int k = 0; k < 10; ++k) {
        if (tid < 64) {
            float v = scores[tid]; int idx = tid;
            if (tid + 64 < T) {
                const float v2 = scores[tid + 64];
                if (v2 > v) { v = v2; idx = tid + 64; }
            }
            for (int off = 32; off > 0; off >>= 1) {
                const float ov = __shfl_xor(v, off);
                const int   oi = __shfl_xor(idx, off);
                if (ov > v || (ov == v && oi < idx)) { v = ov; idx = oi; }
            }
            if (tid == 0) { topi[k] = idx; topv[k] = v; scores[idx] = NEG_F; }
        }
        __syncthreads();
    }

    for (int i = tid; i < 11*D; i += 128) {
        const int j = i / D, d = i % D;
        float v;
        if (j == 0) v = H[(b*T + t)*D + d];
        else        v = (topv[j-1] > -5e29f) ? H[(b*T + topi[j-1])*D + d] : 0.f;
        hist[i] = v;
    }
    __syncthreads();

    // kdot/qdot: 16 dots x 8-way K-split (128 threads), shuffle-reduce in 8-lane groups
    {
        const int dj = tid >> 3, ks = tid & 7;     // dj 0..15
        const float* vec = (dj < 5) ? &qs[dj*D] : &hist[(dj-5)*D];
        const float* vv  = (dj < 5) ? vk : vq;
        float a = 0.f;
#pragma unroll
        for (int d = ks; d < D; d += 8) a = fmaf(vec[d], vv[d], a);
        a += __shfl_xor(a, 1); a += __shfl_xor(a, 2); a += __shfl_xor(a, 4);
        if (ks == 0) { if (dj < 5) kdot[dj] = a; else qdot[dj-5] = a; }
    }
    __syncthreads();

    if (tid < 64) {
        const int i = tid / 11, j = tid - i*11;
        const bool act = tid < 55;
        const bool valid = act && (j == 0 || topv[j-1] > -5e29f);
        float logit = valid ? (kdot[i] + qdot[j]) : NEG_F;
        float mx = logit;
        for (int off = 32; off > 0; off >>= 1) mx = fmaxf(mx, __shfl_xor(mx, off));
        const float e = valid ? expf(logit - mx) : 0.f;
        float inner = 0.f;
        if (act) {
#pragma unroll
            for (int d4 = 0; d4 < D/4; ++d4) {
                const float4 a4 = *(const float4*)&qs[i*D + d4*4];
                const float4 h4 = *(const float4*)&hist[j*D + d4*4];
                inner += a4.x*h4.x + a4.y*h4.y + a4.z*h4.z + a4.w*h4.w;
            }
        }
        float num = e * inner;
        float den = e;
        for (int off = 32; off > 0; off >>= 1) {
            num += __shfl_xor(num, off);
            den += __shfl_xor(den, off);
        }
        if (tid == 0) {
            out[b*T + t + 1] = 1.f/(1.f + expf(-(num/den)));
            if (t == 0) out[b*T] = 0.f;
        }
    }
}

// ---------------------------------------------------------------------------
extern "C" void kernel_launch(void* const* d_in, const int* in_sizes, int n_in,
                              void* d_out, int out_size, void* d_ws, size_t ws_size,
                              hipStream_t stream)
{
    const int*   user     = (const int*)d_in[0];
    const int*   question = (const int*)d_in[1];
    const int*   response = (const int*)d_in[2];
    // d_in[3] = mask (all-true) -- unused
    const int*   qnb   = (const int*)d_in[4];
    const int*   snb   = (const int*)d_in[5];
    const int*   unb   = (const int*)d_in[6];
    const int*   qnb2  = (const int*)d_in[7];
    const int*   skill = (const int*)d_in[8];
    const float* uq    = (const float*)d_in[9];
    const float* emb_q  = (const float*)d_in[10];
    const float* emb_q2 = (const float*)d_in[11];
    const float* emb_s  = (const float*)d_in[12];
    const float* emb_u  = (const float*)d_in[13];
    const float* emb_r  = (const float*)d_in[14];
    const float* w1 = (const float*)d_in[15];
    const float* w2 = (const float*)d_in[16];
    const float* wc = (const float*)d_in[17];
    const float* wp = (const float*)d_in[18];
    const float* wn = (const float*)d_in[19];
    const float* Wih = (const float*)d_in[20];
    const float* Whh = (const float*)d_in[21];
    const float* bih = (const float*)d_in[22];
    const float* bhh = (const float*)d_in[23];
    const float* fusW = (const float*)d_in[24];
    const float* fusb = (const float*)d_in[25];
    const float* aggW = (const float*)d_in[26];
    const float* aggB = (const float*)d_in[27];
    const float* aggLW = (const float*)d_in[28];
    const float* aggLb = (const float*)d_in[29];
    const float* queryW = (const float*)d_in[30];
    const float* keyW   = (const float*)d_in[32];
    const float* attnW  = (const float*)d_in[34];

    float* ws    = (float*)d_ws;
    float* gproj = ws;
    float* H     = gproj + GPROJ_SZ;
    float* vk    = H + H_SZ;
    float* vq    = vk + D;
    float* qagg  = vq + D;
    float* uagg  = qagg + QAGG_SZ;
    float* z2q   = uagg + UAGG_SZ;
    float* z2u   = z2q + Z2Q_SZ;
    float* y1q0  = z2u + Z2U_SZ;
    float* y1q1  = y1q0 + Y1Q_SZ;
    float* y1u0  = y1q1 + Y1Q_SZ;
    float* y1u1  = y1u0 + Y1U_SZ;
    ushort* wb16 = (ushort*)(y1u1 + Y1U_SZ);
    int*   qmark = (int*)((float*)wb16 + WB16_F);
    int*   umark = qmark + Q_N;
    float* out   = (float*)d_out;

    const size_t need = (size_t)(GPROJ_SZ + H_SZ + 2*D + QAGG_SZ + UAGG_SZ
                       + Z2Q_SZ + Z2U_SZ + 2*Y1Q_SZ + 2*Y1U_SZ + WB16_F)*sizeof(float)
                       + (size_t)(Q_N + U_N)*sizeof(int);
    if (ws_size < need) return;

    kMarkInit<<<dim3((Q_N + U_N + 255)/256), dim3(256), 0, stream>>>(qmark);
    kSetup<<<dim3(NB_MK + NB_PK + 1), dim3(256), 0, stream>>>(
        question, user, qmark, umark, Whh, wb16, keyW, queryW, attnW, vk, vq);
    kStageA<<<dim3(NB_Z2Q + NB_Z2U + NB_Y1Q + NB_Y1U), dim3(256), 0, stream>>>(
        qnb, snb, unb, qnb2, emb_q, emb_q2, emb_s, emb_u, uq, wc, wp, wn,
        aggW, aggB, z2q, z2u, y1q0, y1u0);
    kStageB<<<dim3(NB_Y1Q + NB_Y1U), dim3(256), 0, stream>>>(
        snb, qnb2, uq, wc, wp, wn, aggW, aggB, z2q, z2u, y1q0, y1u0, y1q1, y1u1);
    kRoot<<<dim3(Q_N + U_N), dim3(256), 0, stream>>>(
        qmark, umark, qnb, unb, emb_q, emb_u, emb_s, emb_q2,
        y1q0, y1q1, y1u0, y1u1, uq, wc, wp, wn,
        aggW, aggB, aggLW, aggLb, qagg, uagg);
    kFuse<<<dim3(NB_FU), dim3(256), 0, stream>>>(question, user, response, qagg, uagg,
        emb_r, w1, w2, fusW, fusb, Wih, bih, gproj);
    kB<<<dim3(B), dim3(512), 0, stream>>>(gproj, wb16, bhh, H);
    kC<<<dim3(NBT), dim3(128), 0, stream>>>(question, skill, emb_q, emb_s, H, vk, vq, out);
}

// Round 18
// 237.488 us; speedup vs baseline: 1.0502x; 1.0502x over previous
//
#include <hip/hip_runtime.h>
#include <math.h>

#define Q_N 5000
#define S_N 1000
#define U_N 2000
#define D   100
#define B   32
#define T   100
#define NBT (B*(T-1))
#define NEG_F (-1e30f)

// stage-A/B block partitions (16 rows per block)
#define NB_Z2Q ((Q_N+15)/16)   // 313
#define NB_Z2U ((U_N+15)/16)   // 125
#define NB_Y1Q ((S_N+15)/16)   // 63
#define NB_Y1U ((Q_N+15)/16)   // 313
// packed bf16 Whh: 13 m-slices x 400 cols x 8 bf16
#define WB16_U16 (13*400*8)
#define WB16_F   (WB16_U16/2)
// kSetup partitions
#define NB_MK ((NBT+255)/256)        // 13
#define NB_PK ((WB16_U16+255)/256)   // 163
// kFuse batching
#define NB_FU (NBT/16)               // 198 exactly (3168 = 198*16)

// workspace layout (floats)
#define GPROJ_SZ (NBT*4*D)   // 1,267,200
#define H_SZ     (B*T*D)     //   320,000
#define QAGG_SZ  (Q_N*D)
#define UAGG_SZ  (U_N*D)
#define Z2Q_SZ   (Q_N*D)
#define Z2U_SZ   (U_N*D)
#define Y1Q_SZ   (S_N*D)
#define Y1U_SZ   (Q_N*D)

__device__ __forceinline__ void fma4(float4& a, float s, const float4 w) {
    a.x = fmaf(s, w.x, a.x); a.y = fmaf(s, w.y, a.y);
    a.z = fmaf(s, w.z, a.z); a.w = fmaf(s, w.w, a.w);
}
__device__ __forceinline__ float4 relu4(float4 v) {
    v.x = v.x > 0.f ? v.x : 0.f; v.y = v.y > 0.f ? v.y : 0.f;
    v.z = v.z > 0.f ? v.z : 0.f; v.w = v.w > 0.f ? v.w : 0.f;
    return v;
}
__device__ __forceinline__ float4 add4(float4 a, float4 b) {
    a.x += b.x; a.y += b.y; a.z += b.z; a.w += b.w; return a;
}
__device__ __forceinline__ float b2f_lo(unsigned u) { return __uint_as_float(u << 16); }
__device__ __forceinline__ float b2f_hi(unsigned u) { return __uint_as_float(u & 0xffff0000u); }

// ---------------------------------------------------------------------------
// NP=1 matvec (256 thr): dst[c]=relu(src@W+b). K split 8 ways. In-place safe.
// ---------------------------------------------------------------------------
template<int K>
__device__ __forceinline__ void mv100_b256(const float* __restrict__ W,
                                           const float* __restrict__ bias,
                                           const float* __restrict__ src,
                                           float* __restrict__ dst,
                                           float* __restrict__ part)
{
    const int tid = threadIdx.x;
    const int c4  = tid & 31;
    const int ks  = tid >> 5;
    const int col0 = (4*c4 < 96) ? 4*c4 : 96;
    float4 acc = {0.f,0.f,0.f,0.f};
#pragma unroll 2
    for (int d = ks*4; d < K; d += 32) {
        const float4 sv = *(const float4*)&src[d];
        const float4 w0 = *(const float4*)&W[(d+0)*D + col0];
        const float4 w1 = *(const float4*)&W[(d+1)*D + col0];
        const float4 w2 = *(const float4*)&W[(d+2)*D + col0];
        const float4 w3 = *(const float4*)&W[(d+3)*D + col0];
        fma4(acc, sv.x, w0); fma4(acc, sv.y, w1);
        fma4(acc, sv.z, w2); fma4(acc, sv.w, w3);
    }
    *(float4*)&part[ks*D + col0] = acc;
    __syncthreads();
    if (tid < D) {
        float v = bias[tid];
#pragma unroll
        for (int k = 0; k < 8; ++k) v += part[k*D + tid];
        dst[tid] = v > 0.f ? v : 0.f;
    }
    __syncthreads();
}

// ---------------------------------------------------------------------------
// stage16: 16 rows of  out[v] = relu( (self[v] + sum_k f(v,k)*nbEmb[nb_k]) @ W + b )
// ---------------------------------------------------------------------------
struct __align__(16) Stage16 {
    float x[16*D];    // 6.4 KB
    int   nb[128];
    float fw[128];
};

template<int UQ_MODE>
__device__ __forceinline__ void stage16(Stage16& sh, int row0, int N,
        const float* __restrict__ selfEmb, const float* __restrict__ nbEmb,
        const int* __restrict__ tab,
        const float* __restrict__ uq, float wc, float wp, float wn,
        const float* __restrict__ W, const float* __restrict__ bias,
        float* __restrict__ out)
{
    const int tid = threadIdx.x;
    if (tid < 128) {
        const int i = tid >> 3, k = tid & 7;
        int v = row0 + i; if (v >= N) v = N - 1;
        const int nbv = tab[v*8 + k];
        sh.nb[tid] = nbv;
        float f = 0.125f;
        if (UQ_MODE == 1) {
            const float* w = &uq[(v*Q_N + nbv)*3];
            f = 0.125f*(wc*w[0] + wp*w[1] + wn*w[2]);
        } else if (UQ_MODE == 2) {
            const float* w = &uq[(nbv*Q_N + v)*3];
            f = 0.125f*(wc*w[0] + wp*w[1] + wn*w[2]);
        }
        sh.fw[tid] = f;
    }
    __syncthreads();
    const int c4   = tid & 31;
    const int rowg = tid >> 5;                     // 0..7
    const int col0 = (4*c4 < 96) ? 4*c4 : 96;
    // gather + mean + self  -> x
#pragma unroll
    for (int rr = 0; rr < 2; ++rr) {
        const int i = rowg + 8*rr;
        int v = row0 + i; if (v >= N) v = N - 1;
        float4 acc = *(const float4*)&selfEmb[v*D + col0];
#pragma unroll
        for (int k = 0; k < 8; ++k)
            fma4(acc, sh.fw[i*8 + k], *(const float4*)&nbEmb[sh.nb[i*8 + k]*D + col0]);
        *(float4*)&sh.x[i*D + col0] = acc;
    }
    __syncthreads();
    // 16 x D @ D x D  (2 rows, 4 cols per thread)
    float4 a0 = {0.f,0.f,0.f,0.f}, a1 = {0.f,0.f,0.f,0.f};
#pragma unroll 1
    for (int d = 0; d < D; d += 4) {
        const float4 w0 = *(const float4*)&W[(d+0)*D + col0];
        const float4 w1 = *(const float4*)&W[(d+1)*D + col0];
        const float4 w2 = *(const float4*)&W[(d+2)*D + col0];
        const float4 w3 = *(const float4*)&W[(d+3)*D + col0];
        const float4 s0 = *(const float4*)&sh.x[rowg*D + d];
        const float4 s1 = *(const float4*)&sh.x[(rowg+8)*D + d];
        fma4(a0, s0.x, w0); fma4(a0, s0.y, w1); fma4(a0, s0.z, w2); fma4(a0, s0.w, w3);
        fma4(a1, s1.x, w0); fma4(a1, s1.y, w1); fma4(a1, s1.z, w2); fma4(a1, s1.w, w3);
    }
    const float4 bb = *(const float4*)&bias[col0];
    {
        int v = row0 + rowg; if (v >= N) v = N - 1;
        *(float4*)&out[v*D + col0] = relu4(add4(a0, bb));
        v = row0 + rowg + 8; if (v >= N) v = N - 1;
        *(float4*)&out[v*D + col0] = relu4(add4(a1, bb));
    }
}

// ---------------------------------------------------------------------------
// kStageA: z2q | z2u | y1q_it0 | y1u_it0  (all independent)
// ---------------------------------------------------------------------------
__global__ __launch_bounds__(256, 6)
void kStageA(const int* __restrict__ qnb, const int* __restrict__ snb,
             const int* __restrict__ unb, const int* __restrict__ qnb2,
             const float* __restrict__ emb_q, const float* __restrict__ emb_q2,
             const float* __restrict__ emb_s, const float* __restrict__ emb_u,
             const float* __restrict__ uq,
             const float* __restrict__ wcp, const float* __restrict__ wpp,
             const float* __restrict__ wnp,
             const float* __restrict__ aggW, const float* __restrict__ aggB,
             float* __restrict__ z2q, float* __restrict__ z2u,
             float* __restrict__ y1q0, float* __restrict__ y1u0)
{
    __shared__ Stage16 sh;
    const float wc = wcp[0], wp = wpp[0], wn = wnp[0];
    int b = blockIdx.x;
    if (b < NB_Z2Q) {
        stage16<0>(sh, b*16, Q_N, emb_q, emb_s, qnb, uq, wc, wp, wn,
                   aggW + 2*D*D, aggB + 2*D, z2q);
        return;
    }
    b -= NB_Z2Q;
    if (b < NB_Z2U) {
        stage16<1>(sh, b*16, U_N, emb_u, emb_q2, unb, uq, wc, wp, wn,
                   aggW + 2*D*D, aggB + 2*D, z2u);
        return;
    }
    b -= NB_Z2U;
    if (b < NB_Y1Q) {
        stage16<0>(sh, b*16, S_N, emb_s, emb_q, snb, uq, wc, wp, wn,
                   aggW + 1*D*D, aggB + 1*D, y1q0);
        return;
    }
    b -= NB_Y1Q;
    stage16<2>(sh, b*16, Q_N, emb_q2, emb_u, qnb2, uq, wc, wp, wn,
               aggW + 1*D*D, aggB + 1*D, y1u0);
}

// ---------------------------------------------------------------------------
// kStageB: y1q_it1 | y1u_it1 (needs z2*, y1*_it0)
// ---------------------------------------------------------------------------
__global__ __launch_bounds__(256, 6)
void kStageB(const int* __restrict__ snb, const int* __restrict__ qnb2,
             const float* __restrict__ uq,
             const float* __restrict__ wcp, const float* __restrict__ wpp,
             const float* __restrict__ wnp,
             const float* __restrict__ aggW, const float* __restrict__ aggB,
             const float* __restrict__ z2q, const float* __restrict__ z2u,
             const float* __restrict__ y1q0, const float* __restrict__ y1u0,
             float* __restrict__ y1q1, float* __restrict__ y1u1)
{
    __shared__ Stage16 sh;
    const float wc = wcp[0], wp = wpp[0], wn = wnp[0];
    int b = blockIdx.x;
    if (b < NB_Y1Q) {
        stage16<0>(sh, b*16, S_N, y1q0, z2q, snb, uq, wc, wp, wn,
                   aggW + 1*D*D, aggB + 1*D, y1q1);
        return;
    }
    b -= NB_Y1Q;
    stage16<2>(sh, b*16, Q_N, y1u0, z2u, qnb2, uq, wc, wp, wn,
               aggW + 1*D*D, aggB + 1*D, y1u1);
}

// ---------------------------------------------------------------------------
// kMarkInit (separate: kSetup's mark phase depends on it)
// ---------------------------------------------------------------------------
__global__ void kMarkInit(int* __restrict__ marks)
{
    const int i = blockIdx.x*256 + threadIdx.x;
    if (i < Q_N + U_N) marks[i] = 0;
}

// ---------------------------------------------------------------------------
// kSetup: mark | pack-Whh-bf16 | fold  (independent phases, one launch)
// ---------------------------------------------------------------------------
__global__ __launch_bounds__(256)
void kSetup(const int* __restrict__ question, const int* __restrict__ user,
            int* __restrict__ qmark, int* __restrict__ umark,
            const float* __restrict__ Whh, ushort* __restrict__ wb,
            const float* __restrict__ keyW, const float* __restrict__ queryW,
            const float* __restrict__ attnW,
            float* __restrict__ vk, float* __restrict__ vq)
{
    int bkt = blockIdx.x;
    const int tid = threadIdx.x;
    if (bkt < NB_MK) {
        const int bt = bkt*256 + tid;
        if (bt < NBT) {
            const int b = bt / (T-1), t = bt % (T-1);
            qmark[question[b*T + t]] = 1;
            umark[user[b*T + t]] = 1;
        }
        return;
    }
    bkt -= NB_MK;
    if (bkt < NB_PK) {
        const int i = bkt*256 + tid;          // ((m*400)+col)*8 + j
        if (i < WB16_U16) {
            const int j  = i & 7;
            const int mc = i >> 3;
            const int m  = mc / 400;
            const int col = mc - m*400;
            const int d  = 8*m + j;
            ushort v = 0;
            if (d < D) {
                unsigned u = __float_as_uint(Whh[d*4*D + col]);
                const unsigned lsb = (u >> 16) & 1u;
                u += 0x7fffu + lsb;            // round-to-nearest-even
                v = (ushort)(u >> 16);
            }
            wb[i] = v;
        }
        return;
    }
    // fold
    if (tid < D) {
        float a = 0.f;
        for (int e = 0; e < D; ++e) a = fmaf(keyW[tid*D + e], attnW[e], a);
        vk[tid] = a;
    } else if (tid < 2*D) {
        const int d = tid - D;
        float a = 0.f;
        for (int e = 0; e < D; ++e) a = fmaf(queryW[d*D + e], attnW[D + e], a);
        vq[d] = a;
    }
}

// ---------------------------------------------------------------------------
// kRoot: per marked root, 3 root updates + final layer. (r16 version:
// weights streamed from L2, launch_bounds(256,6) -- the r17 LDS-cached
// variant with (256,3) REGRESSED ~11us: occupancy/TLP mattered more than
// the L2 weight re-streaming it saved.)
// ---------------------------------------------------------------------------
struct __align__(16) RootSh {
    float e0[D];
    float part[8*D];
    int   nb[8];
    float fw[8];
};

template<bool WEIGHTED>
__device__ __forceinline__ void rootchain(RootSh& sh, int root,
        const int* __restrict__ tab,
        const float* __restrict__ selfEmb, const float* __restrict__ lvl1Emb,
        const float* __restrict__ y0, const float* __restrict__ y1,
        const float* __restrict__ W0, const float* __restrict__ b0,
        const float* __restrict__ WL, const float* __restrict__ bL,
        const float* __restrict__ uq, float wc, float wp, float wn,
        float* __restrict__ outrow)
{
    const int tid = threadIdx.x;
    if (tid < 8) {
        const int a = tab[root*8 + tid];
        sh.nb[tid] = a;
        float f = 0.125f;
        if (WEIGHTED) {
            const float* w = &uq[(root*Q_N + a)*3];
            f = 0.125f*(wc*w[0] + wp*w[1] + wn*w[2]);
        }
        sh.fw[tid] = f;
    }
    __syncthreads();
    const int c4 = tid & 31;
    const int col0 = (4*c4 < 96) ? 4*c4 : 96;
    // m0
    if (tid < 32) {
        float4 acc = *(const float4*)&selfEmb[root*D + col0];
#pragma unroll
        for (int k = 0; k < 8; ++k)
            fma4(acc, sh.fw[k], *(const float4*)&lvl1Emb[sh.nb[k]*D + col0]);
        *(float4*)&sh.e0[col0] = acc;
    }
    __syncthreads();
    mv100_b256<D>(W0, b0, sh.e0, sh.e0, sh.part);
    // m1
    if (tid < 32) {
        float4 acc = *(const float4*)&sh.e0[col0];
#pragma unroll
        for (int k = 0; k < 8; ++k)
            fma4(acc, sh.fw[k], *(const float4*)&y0[sh.nb[k]*D + col0]);
        *(float4*)&sh.e0[col0] = acc;
    }
    __syncthreads();
    mv100_b256<D>(W0, b0, sh.e0, sh.e0, sh.part);
    // m2
    if (tid < 32) {
        float4 acc = *(const float4*)&sh.e0[col0];
#pragma unroll
        for (int k = 0; k < 8; ++k)
            fma4(acc, sh.fw[k], *(const float4*)&y1[sh.nb[k]*D + col0]);
        *(float4*)&sh.e0[col0] = acc;
    }
    __syncthreads();
    mv100_b256<D>(W0, b0, sh.e0, sh.e0, sh.part);
    // final layer -> global
    mv100_b256<D>(WL, bL, sh.e0, outrow, sh.part);
}

__global__ __launch_bounds__(256, 6)
void kRoot(const int* __restrict__ qmark, const int* __restrict__ umark,
           const int* __restrict__ qnb, const int* __restrict__ unb,
           const float* __restrict__ emb_q, const float* __restrict__ emb_u,
           const float* __restrict__ emb_s, const float* __restrict__ emb_q2,
           const float* __restrict__ y1q0, const float* __restrict__ y1q1,
           const float* __restrict__ y1u0, const float* __restrict__ y1u1,
           const float* __restrict__ uq,
           const float* __restrict__ wcp, const float* __restrict__ wpp,
           const float* __restrict__ wnp,
           const float* __restrict__ aggW, const float* __restrict__ aggB,
           const float* __restrict__ aggLW, const float* __restrict__ aggLb,
           float* __restrict__ qagg, float* __restrict__ uagg)
{
    __shared__ RootSh sh;
    const int b = blockIdx.x;
    if (b < Q_N) {
        if (!qmark[b]) return;
        rootchain<false>(sh, b, qnb, emb_q, emb_s, y1q0, y1q1,
                         aggW, aggB, aggLW, aggLb,
                         uq, 0.f, 0.f, 0.f, qagg + b*D);
    } else {
        const int u = b - Q_N;
        if (!umark[u]) return;
        rootchain<true>(sh, u, unb, emb_u, emb_q2, y1u0, y1u1,
                        aggW, aggB, aggLW, aggLb,
                        uq, wcp[0], wpp[0], wnp[0], uagg + u*D);
    }
}

// ---------------------------------------------------------------------------
// kFuse: 16 (b,t) rows per block (198 blocks). Stages xcat + evec^T in LDS
// so fusW/Wih are streamed ONCE per 16 rows (kept from r17 for attribution).
// ---------------------------------------------------------------------------
__global__ __launch_bounds__(256)
void kFuse(const int* __restrict__ question, const int* __restrict__ user,
           const int* __restrict__ response,
           const float* __restrict__ qagg, const float* __restrict__ uagg,
           const float* __restrict__ emb_r,
           const float* __restrict__ w1p, const float* __restrict__ w2p,
           const float* __restrict__ fusW, const float* __restrict__ fusb,
           const float* __restrict__ Wih, const float* __restrict__ bih,
           float* __restrict__ gproj)
{
    __shared__ __align__(16) float x[16][2*D];      // 12.8 KB
    __shared__ __align__(16) float evecT[D][20];    // 8 KB (16 rows + 4 pad)
    const int row0 = blockIdx.x * 16;
    const int tid = threadIdx.x;
    const float w1 = w1p[0], w2 = w2p[0];
    // phase 0: gather 16 xcat rows (50 float4 per row)
#pragma unroll 1
    for (int idx = tid; idx < 16*50; idx += 256) {
        const int i = idx / 50, c4 = idx - i*50;
        const int bt = row0 + i;
        const int b = bt / (T-1), t = bt - b*(T-1);
        const int col0 = c4*4;
        float4 v;
        if (col0 < D) {
            const int q = question[b*T + t];
            const int u = user[b*T + t];
            const float4 qa = *(const float4*)&qagg[q*D + col0];
            const float4 ua = *(const float4*)&uagg[u*D + col0];
            v.x = w1*qa.x + w2*ua.x; v.y = w1*qa.y + w2*ua.y;
            v.z = w1*qa.z + w2*ua.z; v.w = w1*qa.w + w2*ua.w;
        } else {
            const int r = response[b*T + t];
            v = *(const float4*)&emb_r[r*D + (col0 - D)];
        }
        *(float4*)&x[i][col0] = v;
    }
    __syncthreads();
    // phase 1: 16 x 200 @ 200 x 100 -> evecT (transposed store)
    {
        const int c4 = tid & 31;
        const int rowg = tid >> 5;
        const int col0 = (4*c4 < 96) ? 4*c4 : 96;
        float4 a0 = {0.f,0.f,0.f,0.f}, a1 = {0.f,0.f,0.f,0.f};
#pragma unroll 2
        for (int d = 0; d < 2*D; d += 4) {
            const float4 w0v = *(const float4*)&fusW[(d+0)*D + col0];
            const float4 w1v = *(const float4*)&fusW[(d+1)*D + col0];
            const float4 w2v = *(const float4*)&fusW[(d+2)*D + col0];
            const float4 w3v = *(const float4*)&fusW[(d+3)*D + col0];
            const float4 s0 = *(const float4*)&x[rowg][d];
            const float4 s1 = *(const float4*)&x[rowg+8][d];
            fma4(a0, s0.x, w0v); fma4(a0, s0.y, w1v);
            fma4(a0, s0.z, w2v); fma4(a0, s0.w, w3v);
            fma4(a1, s1.x, w0v); fma4(a1, s1.y, w1v);
            fma4(a1, s1.z, w2v); fma4(a1, s1.w, w3v);
        }
        const float4 bb = *(const float4*)&fusb[col0];
        a0 = relu4(add4(a0, bb)); a1 = relu4(add4(a1, bb));
        evecT[col0+0][rowg] = a0.x; evecT[col0+1][rowg] = a0.y;
        evecT[col0+2][rowg] = a0.z; evecT[col0+3][rowg] = a0.w;
        evecT[col0+0][rowg+8] = a1.x; evecT[col0+1][rowg+8] = a1.y;
        evecT[col0+2][rowg+8] = a1.z; evecT[col0+3][rowg+8] = a1.w;
    }
    __syncthreads();
    // phase 2: gproj rows = evec @ Wih + bih (Wih streamed once per block)
    {
        const int c  = tid & 127;          // col chunk (0..99 active)
        const int rh = tid >> 7;           // 0,1 -> rows rh*8 .. rh*8+7
        if (c < D) {
            const int col0 = 4*c;
            float4 acc[8];
#pragma unroll
            for (int r = 0; r < 8; ++r) acc[r] = {0.f,0.f,0.f,0.f};
#pragma unroll 2
            for (int k = 0; k < D; ++k) {
                const float4 wv = *(const float4*)&Wih[k*4*D + col0];
                const float4 e0 = *(const float4*)&evecT[k][rh*8];
                const float4 e1 = *(const float4*)&evecT[k][rh*8 + 4];
                fma4(acc[0], e0.x, wv); fma4(acc[1], e0.y, wv);
                fma4(acc[2], e0.z, wv); fma4(acc[3], e0.w, wv);
                fma4(acc[4], e1.x, wv); fma4(acc[5], e1.y, wv);
                fma4(acc[6], e1.z, wv); fma4(acc[7], e1.w, wv);
            }
            const float4 bb = *(const float4*)&bih[col0];
#pragma unroll
            for (int r = 0; r < 8; ++r) {
                const int bt = row0 + rh*8 + r;
                *(float4*)&gproj[bt*4*D + col0] = add4(acc[r], bb);
            }
        }
    }
}

// ---------------------------------------------------------------------------
// kB: LSTM scan, one block per b, 512 threads (400 active).
// PROVEN BEST (r13/r16: 89.5-89.8us, VGPR=88). bf16 weights (13 named uint4
// = 52 VGPR) resident under waves_per_eu(2,2); h read as LDS float4
// broadcasts; nonlinearity fused into the matvec phase.
// ---------------------------------------------------------------------------
#define KB_LDW(m) const uint4 W##m = wp[m*400 + col];
#define KB_FMA(m) { const float4 h0 = *(const float4*)&hbuf[8*m]; \
                    const float4 h1 = *(const float4*)&hbuf[8*m + 4]; \
    a0 = fmaf(h0.x, b2f_lo(W##m.x), a0); \
    a1 = fmaf(h0.y, b2f_hi(W##m.x), a1); \
    a2 = fmaf(h0.z, b2f_lo(W##m.y), a2); \
    a3 = fmaf(h0.w, b2f_hi(W##m.y), a3); \
    a0 = fmaf(h1.x, b2f_lo(W##m.z), a0); \
    a1 = fmaf(h1.y, b2f_hi(W##m.z), a1); \
    a2 = fmaf(h1.z, b2f_lo(W##m.w), a2); \
    a3 = fmaf(h1.w, b2f_hi(W##m.w), a3); }

__global__ __attribute__((amdgpu_flat_work_group_size(512, 512)))
           __attribute__((amdgpu_waves_per_eu(2, 2)))
void kB(const float* __restrict__ gproj, const ushort* __restrict__ wb,
        const float* __restrict__ bhh, float* __restrict__ H)
{
    __shared__ __align__(16) float hbuf[104];     // [100..103] stay 0 (pad)
    __shared__ float gates[4*D];                  // post-nonlinearity values
    const int b = blockIdx.x;
    const int tid = threadIdx.x;
    const bool on = tid < 4*D;
    const int col = on ? tid : (4*D - 1);
    const float bb = bhh[col];
    const bool isG = (col >= 2*D) && (col < 3*D); // gg column -> tanh
    const uint4* wp = (const uint4*)wb;
    // hoisted loop-invariant bf16 weights (13 x uint4 = 52 VGPR, resident)
    KB_LDW(0)  KB_LDW(1)  KB_LDW(2)  KB_LDW(3)  KB_LDW(4)  KB_LDW(5)
    KB_LDW(6)  KB_LDW(7)  KB_LDW(8)  KB_LDW(9)  KB_LDW(10) KB_LDW(11)
    KB_LDW(12)
    float creg = 0.f;
    if (tid < 104) hbuf[tid] = 0.f;
    float g = on ? gproj[(b*(T-1) + 0)*4*D + col] : 0.f;
    __syncthreads();
#pragma unroll 1
    for (int t = 0; t < T-1; ++t) {
        if (on) {
            float a0 = g + bb, a1 = 0.f, a2 = 0.f, a3 = 0.f;
            KB_FMA(0)  KB_FMA(1)  KB_FMA(2)  KB_FMA(3)  KB_FMA(4)  KB_FMA(5)
            KB_FMA(6)  KB_FMA(7)  KB_FMA(8)  KB_FMA(9)  KB_FMA(10) KB_FMA(11)
            KB_FMA(12)
            const float tot = (a0 + a1) + (a2 + a3);
            gates[col] = isG ? tanhf(tot) : 1.f/(1.f + expf(-tot));
        }
        __syncthreads();
        // prefetch next step's gproj under the combine phase
        if (t + 1 < T-1 && on) g = gproj[(b*(T-1) + t + 1)*4*D + col];
        if (tid < D) {
            const float ig = gates[tid];
            const float fg = gates[D   + tid];
            const float gg = gates[2*D + tid];
            const float og = gates[3*D + tid];
            const float cn = fg*creg + ig*gg;
            const float hn = og*tanhf(cn);
            creg = cn;
            hbuf[tid] = hn;
            H[(b*T + t)*D + tid] = hn;
        }
        __syncthreads();
    }
}

// ---------------------------------------------------------------------------
// kC: prediction head per (b,t): scores -> top-10 -> attention -> sigmoid
// ---------------------------------------------------------------------------
__global__ __launch_bounds__(128)
void kC(const int* __restrict__ question, const int* __restrict__ skill_tab,
        const float* __restrict__ emb_q, const float* __restrict__ emb_s,
        const float* __restrict__ H, const float* __restrict__ vk,
        const float* __restrict__ vq, float* __restrict__ out)
{
    __shared__ __align__(16) float qs[5*D];
    __shared__ __align__(16) float hist[11*D];
    __shared__ float scores[T];
    __shared__ float kdot[5], qdot[11];
    __shared__ int   topi[10];
    __shared__ float topv[10];
    const int blk = blockIdx.x;
    const int b = blk / (T-1);
    const int t = blk % (T-1);
    const int tid = threadIdx.x;
    const int qn = question[b*T + t + 1];

    for (int i = tid; i < 5*D; i += 128) {
        const int rr = i / D, d = i % D;
        if (rr == 0) qs[i] = emb_q[qn*D + d];
        else         qs[i] = emb_s[skill_tab[qn*4 + (rr-1)]*D + d];
    }
    __syncthreads();

    for (int tau = tid; tau < T; tau += 128) {
        float sc = NEG_F;
        if (tau < t) {
            const float4* rowp = (const float4*)&emb_q[question[b*T + tau]*D];
            float acc = 0.f;
#pragma unroll 1
            for (int d4 = 0; d4 < D/4; ++d4) {
                const float4 a  = rowp[d4];
                const float4 qv = *(const float4*)&qs[d4*4];
                acc += a.x*qv.x + a.y*qv.y + a.z*qv.z + a.w*qv.w;
            }
            sc = acc;
        }
        scores[tau] = sc;
    }
    __syncthreads();

    // top-10 (lowest-index wins ties; only the selected SET matters)
    for (int k = 0; k < 10; ++k) {
        if (tid < 64) {
            float v = scores[tid]; int idx = tid;
            if (tid + 64 < T) {
                const float v2 = scores[tid + 64];
                if (v2 > v) { v = v2; idx = tid + 64; }
            }
            for (int off = 32; off > 0; off >>= 1) {
                const float ov = __shfl_xor(v, off);
                const int   oi = __shfl_xor(idx, off);
                if (ov > v || (ov == v && oi < idx)) { v = ov; idx = oi; }
            }
            if (tid == 0) { topi[k] = idx; topv[k] = v; scores[idx] = NEG_F; }
        }
        __syncthreads();
    }

    for (int i = tid; i < 11*D; i += 128) {
        const int j = i / D, d = i % D;
        float v;
        if (j == 0) v = H[(b*T + t)*D + d];
        else        v = (topv[j-1] > -5e29f) ? H[(b*T + topi[j-1])*D + d] : 0.f;
        hist[i] = v;
    }
    __syncthreads();

    // kdot/qdot: 16 dots x 8-way K-split (128 threads), shuffle-reduce in 8-lane groups
    {
        const int dj = tid >> 3, ks = tid & 7;     // dj 0..15
        const float* vec = (dj < 5) ? &qs[dj*D] : &hist[(dj-5)*D];
        const float* vv  = (dj < 5) ? vk : vq;
        float a = 0.f;
#pragma unroll
        for (int d = ks; d < D; d += 8) a = fmaf(vec[d], vv[d], a);
        a += __shfl_xor(a, 1); a += __shfl_xor(a, 2); a += __shfl_xor(a, 4);
        if (ks == 0) { if (dj < 5) kdot[dj] = a; else qdot[dj-5] = a; }
    }
    __syncthreads();

    if (tid < 64) {
        const int i = tid / 11, j = tid - i*11;
        const bool act = tid < 55;
        const bool valid = act && (j == 0 || topv[j-1] > -5e29f);
        float logit = valid ? (kdot[i] + qdot[j]) : NEG_F;
        float mx = logit;
        for (int off = 32; off > 0; off >>= 1) mx = fmaxf(mx, __shfl_xor(mx, off));
        const float e = valid ? expf(logit - mx) : 0.f;
        float inner = 0.f;
        if (act) {
#pragma unroll
            for (int d4 = 0; d4 < D/4; ++d4) {
                const float4 a4 = *(const float4*)&qs[i*D + d4*4];
                const float4 h4 = *(const float4*)&hist[j*D + d4*4];
                inner += a4.x*h4.x + a4.y*h4.y + a4.z*h4.z + a4.w*h4.w;
            }
        }
        float num = e * inner;
        float den = e;
        for (int off = 32; off > 0; off >>= 1) {
            num += __shfl_xor(num, off);
            den += __shfl_xor(den, off);
        }
        if (tid == 0) {
            out[b*T + t + 1] = 1.f/(1.f + expf(-(num/den)));
            if (t == 0) out[b*T] = 0.f;
        }
    }
}

// ---------------------------------------------------------------------------
extern "C" void kernel_launch(void* const* d_in, const int* in_sizes, int n_in,
                              void* d_out, int out_size, void* d_ws, size_t ws_size,
                              hipStream_t stream)
{
    const int*   user     = (const int*)d_in[0];
    const int*   question = (const int*)d_in[1];
    const int*   response = (const int*)d_in[2];
    // d_in[3] = mask (all-true) -- unused
    const int*   qnb   = (const int*)d_in[4];
    const int*   snb   = (const int*)d_in[5];
    const int*   unb   = (const int*)d_in[6];
    const int*   qnb2  = (const int*)d_in[7];
    const int*   skill = (const int*)d_in[8];
    const float* uq    = (const float*)d_in[9];
    const float* emb_q  = (const float*)d_in[10];
    const float* emb_q2 = (const float*)d_in[11];
    const float* emb_s  = (const float*)d_in[12];
    const float* emb_u  = (const float*)d_in[13];
    const float* emb_r  = (const float*)d_in[14];
    const float* w1 = (const float*)d_in[15];
    const float* w2 = (const float*)d_in[16];
    const float* wc = (const float*)d_in[17];
    const float* wp = (const float*)d_in[18];
    const float* wn = (const float*)d_in[19];
    const float* Wih = (const float*)d_in[20];
    const float* Whh = (const float*)d_in[21];
    const float* bih = (const float*)d_in[22];
    const float* bhh = (const float*)d_in[23];
    const float* fusW = (const float*)d_in[24];
    const float* fusb = (const float*)d_in[25];
    const float* aggW = (const float*)d_in[26];
    const float* aggB = (const float*)d_in[27];
    const float* aggLW = (const float*)d_in[28];
    const float* aggLb = (const float*)d_in[29];
    const float* queryW = (const float*)d_in[30];
    const float* keyW   = (const float*)d_in[32];
    const float* attnW  = (const float*)d_in[34];

    float* ws    = (float*)d_ws;
    float* gproj = ws;
    float* H     = gproj + GPROJ_SZ;
    float* vk    = H + H_SZ;
    float* vq    = vk + D;
    float* qagg  = vq + D;
    float* uagg  = qagg + QAGG_SZ;
    float* z2q   = uagg + UAGG_SZ;
    float* z2u   = z2q + Z2Q_SZ;
    float* y1q0  = z2u + Z2U_SZ;
    float* y1q1  = y1q0 + Y1Q_SZ;
    float* y1u0  = y1q1 + Y1Q_SZ;
    float* y1u1  = y1u0 + Y1U_SZ;
    ushort* wb16 = (ushort*)(y1u1 + Y1U_SZ);
    int*   qmark = (int*)((float*)wb16 + WB16_F);
    int*   umark = qmark + Q_N;
    float* out   = (float*)d_out;

    const size_t need = (size_t)(GPROJ_SZ + H_SZ + 2*D + QAGG_SZ + UAGG_SZ
                       + Z2Q_SZ + Z2U_SZ + 2*Y1Q_SZ + 2*Y1U_SZ + WB16_F)*sizeof(float)
                       + (size_t)(Q_N + U_N)*sizeof(int);
    if (ws_size < need) return;

    kMarkInit<<<dim3((Q_N + U_N + 255)/256), dim3(256), 0, stream>>>(qmark);
    kSetup<<<dim3(NB_MK + NB_PK + 1), dim3(256), 0, stream>>>(
        question, user, qmark, umark, Whh, wb16, keyW, queryW, attnW, vk, vq);
    kStageA<<<dim3(NB_Z2Q + NB_Z2U + NB_Y1Q + NB_Y1U), dim3(256), 0, stream>>>(
        qnb, snb, unb, qnb2, emb_q, emb_q2, emb_s, emb_u, uq, wc, wp, wn,
        aggW, aggB, z2q, z2u, y1q0, y1u0);
    kStageB<<<dim3(NB_Y1Q + NB_Y1U), dim3(256), 0, stream>>>(
        snb, qnb2, uq, wc, wp, wn, aggW, aggB, z2q, z2u, y1q0, y1u0, y1q1, y1u1);
    kRoot<<<dim3(Q_N + U_N), dim3(256), 0, stream>>>(
        qmark, umark, qnb, unb, emb_q, emb_u, emb_s, emb_q2,
        y1q0, y1q1, y1u0, y1u1, uq, wc, wp, wn,
        aggW, aggB, aggLW, aggLb, qagg, uagg);
    kFuse<<<dim3(NB_FU), dim3(256), 0, stream>>>(question, user, response, qagg, uagg,
        emb_r, w1, w2, fusW, fusb, Wih, bih, gproj);
    kB<<<dim3(B), dim3(512), 0, stream>>>(gproj, wb16, bhh, H);
    kC<<<dim3(NBT), dim3(128), 0, stream>>>(question, skill, emb_q, emb_s, H, vk, vq, out);
}